// Round 2
// baseline (349.396 us; speedup 1.0000x reference)
//
#include <hip/hip_runtime.h>
#include <math.h>

#define N_ANT 64
#define BATCH 131072
#define NSTEPS 63   // 31 internal softmax units + 32 leaf groups, DFS preorder
#define TPB 128

typedef float v2f __attribute__((ext_vector_type(2)));
typedef float v4f __attribute__((ext_vector_type(4)));

static __device__ __forceinline__ v4f vfma4(v4f a, v4f b, v4f c) {
#if __has_builtin(__builtin_elementwise_fma)
    return __builtin_elementwise_fma(a, b, c);
#else
    v4f r; r.x = fmaf(a.x,b.x,c.x); r.y = fmaf(a.y,b.y,c.y);
    r.z = fmaf(a.z,b.z,c.z); r.w = fmaf(a.w,b.w,c.w); return r;
#endif
}

static __device__ __forceinline__ float hsum4(v4f v) {
    return (v.x + v.y) + (v.z + v.w);
}

static __device__ __forceinline__ float fast_rcp(float x) {
#if __has_builtin(__builtin_amdgcn_rcpf)
    return __builtin_amdgcn_rcpf(x);
#else
    return 1.0f / x;
#endif
}

// Advance DFS-preorder state over the complete binary tree.
// Internal units: l=0..4 (node n at layer l). Leaf groups: l==5 (group n).
static __device__ __forceinline__ void dfs_next(int& l, int& n) {
    if (l < 5) { l = l + 1; n = 2 * n; }
    else {
        while (n & 1) { n >>= 1; l--; }
        n += 1;
    }
}

// Build combined real weight buffer in DFS-step order.
// Unit s occupies W[s*256 .. s*256+255]:
//   [  0.. 63] col0 w_re[a]   [ 64..127] col0 w_im[a]
//   [128..191] col1 w_re[a]   [192..255] col1 w_im[a]
__global__ void fill_weights(const float* __restrict__ t0, const float* __restrict__ t1,
                             const float* __restrict__ t2, const float* __restrict__ t3,
                             const float* __restrict__ t4, float* __restrict__ W) {
    const int s = blockIdx.x;
    const int a = threadIdx.x;  // antenna index 0..63
    int l = 0, n = 0;
    for (int i = 0; i < s; ++i) dfs_next(l, n);
    float* w = W + s * 256;
    const float inv = 0.125f;  // 1/sqrt(64)
    if (l < 5) {
        const float* th = (l == 0) ? t0 : (l == 1) ? t1 : (l == 2) ? t2 : (l == 3) ? t3 : t4;
        float th0 = th[(n * N_ANT + a) * 2 + 0];
        float th1 = th[(n * N_ANT + a) * 2 + 1];
        float s0, c0, s1, c1;
        sincosf(th0, &s0, &c0);
        sincosf(th1, &s1, &c1);
        w[0   + a] = c0 * inv;  w[64  + a] = s0 * inv;
        w[128 + a] = c1 * inv;  w[192 + a] = s1 * inv;
    } else {
        // Leaf DFT codebook columns 2n, 2n+1 (numpy computes in float64 then casts).
        const double step = (cos(M_PI - 1e-6) - 1.0) / 63.0;
        for (int k = 0; k < 2; ++k) {
            int c = 2 * n + k;
            double cosaz = 1.0 + (double)c * step;
            double ph = M_PI * (double)a * cosaz;
            w[128 * k + 0  + a] = (float)(cos(ph) * 0.125);
            w[128 * k + 64 + a] = (float)(sin(ph) * 0.125);
        }
    }
}

__global__ __launch_bounds__(TPB) void beam_tree(const float* __restrict__ x,
                                                 const float* __restrict__ W,
                                                 float* __restrict__ out) {
    // Output staging: row stride 66 words (even -> 8B-aligned v2f slots; 66%32=2
    // -> ds_*_b64 lands 2 lanes/bank = free). Flushed coalesced at the end.
    __shared__ float stg[TPB * 66];
    // Per-thread 5-level DFS probability stack; stride 11 (odd) -> 2 lanes/bank.
    __shared__ float stk[TPB * 11];

    const int tid = threadIdx.x;
    const int e = blockIdx.x * TPB + tid;

    // Load x row: [re(0..63) | im(0..63)], keep fully in VGPRs.
    const float4* px = (const float4*)(x + (size_t)e * 128);
    v4f xr[16], xi[16];
#pragma unroll
    for (int j = 0; j < 16; ++j) { float4 v = px[j];      xr[j] = (v4f){v.x, v.y, v.z, v.w}; }
#pragma unroll
    for (int j = 0; j < 16; ++j) { float4 v = px[16 + j]; xi[j] = (v4f){v.x, v.y, v.z, v.w}; }

    float* st = stk + tid * 11;
    float* sr = stg + tid * 66;

    int l = 0, n = 0, g = 0;
    for (int s = 0; s < NSTEPS; ++s) {
        const float* wu = W + s * 256;  // thread-uniform -> expect scalar loads
        v4f arr = {0,0,0,0}, ari = {0,0,0,0}, air = {0,0,0,0}, aii = {0,0,0,0};
        v4f brr = {0,0,0,0}, bri = {0,0,0,0}, bir = {0,0,0,0}, bii = {0,0,0,0};
#pragma unroll
        for (int t = 0; t < 16; ++t) {
            v4f w0re = *(const v4f*)(wu + 4 * t);
            v4f w0im = *(const v4f*)(wu + 64 + 4 * t);
            v4f w1re = *(const v4f*)(wu + 128 + 4 * t);
            v4f w1im = *(const v4f*)(wu + 192 + 4 * t);
            v4f xrt = xr[t], xit = xi[t];
            arr = vfma4(xrt, w0re, arr);
            ari = vfma4(xrt, w0im, ari);
            air = vfma4(xit, w0re, air);
            aii = vfma4(xit, w0im, aii);
            brr = vfma4(xrt, w1re, brr);
            bri = vfma4(xrt, w1im, bri);
            bir = vfma4(xit, w1re, bir);
            bii = vfma4(xit, w1im, bii);
        }
        // complex dot: re = xr.wre - xi.wim ; im = xr.wim + xi.wre
        float y0r = hsum4(arr) - hsum4(aii);
        float y0i = hsum4(ari) + hsum4(air);
        float y1r = hsum4(brr) - hsum4(bii);
        float y1i = hsum4(bri) + hsum4(bir);
        float g0 = fmaf(y0r, y0r, y0i * y0i);
        float g1 = fmaf(y1r, y1r, y1i * y1i);
        // 2-way softmax (max-subtracted, matches jax.nn.softmax)
        float m  = fmaxf(g0, g1);
        float e0 = __expf(g0 - m);
        float e1 = __expf(g1 - m);
        float inv = fast_rcp(e0 + e1);
        float p0 = e0 * inv, p1 = e1 * inv;

        float pme = (l == 0) ? 1.0f : st[(l - 1) * 2 + (n & 1)];
        if (l < 5) {
            st[l * 2 + 0] = pme * p0;
            st[l * 2 + 1] = pme * p1;
        } else {
            *(v2f*)(sr + 2 * g) = (v2f){pme * p0, pme * p1};  // ds_write_b64, aligned
            g++;
        }
        dfs_next(l, n);
    }

    // Coalesced flush: block's 128 rows x 64 floats = 32 KB contiguous in out.
    __syncthreads();
    float4* ob = (float4*)(out + (size_t)blockIdx.x * TPB * 64);
#pragma unroll
    for (int k = 0; k < 16; ++k) {
        int fidx = k * TPB + tid;        // float4 index within block tile
        int row = fidx >> 4;             // 16 float4 per row
        int col = (fidx & 15) * 4;
        const float* sp = stg + row * 66 + col;
        v2f a = *(const v2f*)(sp);       // ds_read_b64 x2 (stride 66 is only 8B-aligned)
        v2f b = *(const v2f*)(sp + 2);
        ob[fidx] = make_float4(a.x, a.y, b.x, b.y);
    }
}

extern "C" void kernel_launch(void* const* d_in, const int* in_sizes, int n_in,
                              void* d_out, int out_size, void* d_ws, size_t ws_size,
                              hipStream_t stream) {
    const float* x  = (const float*)d_in[0];
    const float* t0 = (const float*)d_in[1];
    const float* t1 = (const float*)d_in[2];
    const float* t2 = (const float*)d_in[3];
    const float* t3 = (const float*)d_in[4];
    const float* t4 = (const float*)d_in[5];
    float* W = (float*)d_ws;  // 63*256*4 = 64.5 KB, rebuilt every call (ws re-poisoned)

    fill_weights<<<dim3(NSTEPS), dim3(N_ANT), 0, stream>>>(t0, t1, t2, t3, t4, W);
    beam_tree<<<dim3(BATCH / TPB), dim3(TPB), 0, stream>>>(x, W, (float*)d_out);
}